// Round 14
// baseline (131.931 us; speedup 1.0000x reference)
//
#include <hip/hip_runtime.h>
#include <math.h>

#define THREADS 256
#define HW 2304

typedef __attribute__((ext_vector_type(8))) short short8;
typedef __attribute__((ext_vector_type(4))) float f32x4;
typedef __attribute__((ext_vector_type(8))) unsigned short us8;

typedef const __attribute__((address_space(1))) void* gas_p;
typedef __attribute__((address_space(3))) void* las_p;

__device__ __forceinline__ void gll16(const void* g, const void* l) {
    __builtin_amdgcn_global_load_lds((gas_p)g, (las_p)l, 16, 0, 0);
}

// ---- generic LDS staging: zero-padded halo rows ----
__device__ __forceinline__ void stage_rows(const float* __restrict__ src, float* __restrict__ dst,
                                           int nch, int chStride, int H, int W,
                                           int rlo, int rcount, int tid, int nthr, bool relu) {
    int rowfl = W + 4;
    int total = nch * rcount * rowfl;
    float4 z = make_float4(0.f, 0.f, 0.f, 0.f);
    for (int i = tid; i * 4 < total; i += nthr) ((float4*)dst)[i] = z;
    __syncthreads();
    int w2 = W >> 1;
    int m = nch * rcount * w2;
    for (int i = tid; i < m; i += nthr) {
        int c2 = i % w2;
        int rr = (i / w2) % rcount;
        int ch = i / (w2 * rcount);
        int srow = rlo + rr;
        if (srow < 0 || srow >= H) continue;
        float2 v = *(const float2*)(src + (size_t)ch * chStride + srow * W + 2 * c2);
        if (relu) { v.x = fmaxf(v.x, 0.f); v.y = fmaxf(v.y, 0.f); }
        *(float2*)(dst + (size_t)ch * rcount * rowfl + rr * rowfl + 2 + 2 * c2) = v;
    }
    __syncthreads();
}

#define LOAD_W9(wlbase, ci)                                        \
    const float4* wp4 = (const float4*)((wlbase) + (ci) * 12);     \
    float4 wa = wp4[0], wb = wp4[1], wc = wp4[2];                  \
    const float w9[9] = {wa.x, wa.y, wa.z, wa.w, wb.x, wb.y, wb.z, wb.w, wc.x};

// ---- embedding conv body (global src) + norm + bf16 hi/lo split ----
__device__ __forceinline__ void emb_body(const float* __restrict__ src, int arr, int ni, int pt,
                                         const float* __restrict__ ew, const float* __restrict__ eb,
                                         unsigned short* __restrict__ hl, float* __restrict__ nrm,
                                         float* wl, int tid, int nthr) {
    for (int i = tid; i < 900; i += nthr) wl[(i / 9) * 12 + (i % 9)] = ew[i];
    for (int i = tid; i < 100; i += nthr) wl[1200 + i] = eb[i];
    __syncthreads();

    int pix = pt * 256 + tid;
    int x = pix % 48, y = pix / 48;
    float p9[9];
    #pragma unroll
    for (int ky = 0; ky < 3; ++ky)
        #pragma unroll
        for (int kx = 0; kx < 3; ++kx) {
            int yy = y + ky - 1, xx = x + kx - 1;
            p9[ky * 3 + kx] = (yy >= 0 && yy < 48 && xx >= 0 && xx < 48) ? src[yy * 48 + xx] : 0.f;
        }

    float nsum = 0.f;
    char* rowp = (char*)(hl + (((size_t)(arr * 4 + ni)) * HW + pix) * 256);
    for (int g = 0; g < 16; ++g) {
        us8 vh, vl;
        #pragma unroll
        for (int j = 0; j < 8; ++j) {
            int e = g * 8 + j;
            float v = 0.f;
            if (e < 100) {
                v = wl[1200 + e];
                #pragma unroll
                for (int k = 0; k < 9; ++k) v = fmaf(p9[k], wl[e * 12 + k], v);
                nsum = fmaf(v, v, nsum);
            }
            unsigned bits = __float_as_uint(v);
            vh[j] = (unsigned short)(bits >> 16);
            float lo = v - __uint_as_float(bits & 0xFFFF0000u);
            vl[j] = (unsigned short)(__float_as_uint(lo) >> 16);
        }
        *(us8*)(rowp + g * 16) = vh;
        *(us8*)(rowp + 256 + g * 16) = vl;
    }
    nrm[(size_t)(arr * 4 + ni) * HW + pix] = nsum;
}

// ---- k_pre (r4-verified): bias-init, embprep(x1,x2), inf-init, enc1pool. grid 608 ----
__global__ __launch_bounds__(256) void k_pre(
        float* __restrict__ d2b, float* __restrict__ d1b,
        const float* __restrict__ b2, const float* __restrict__ b1,
        const float* __restrict__ x1, const float* __restrict__ x2,
        const float* __restrict__ ew, const float* __restrict__ eb,
        unsigned short* __restrict__ hl, float* __restrict__ nrm,
        unsigned* __restrict__ initbuf,
        const float* __restrict__ x3, const float* __restrict__ e1w,
        const float* __restrict__ e1b, float* __restrict__ e1u, float* __restrict__ p1) {
    __shared__ __align__(16) float lds[3 * 50 * 52];
    __shared__ __align__(16) float wl1[48];
    __shared__ float wl[1300];
    int bx = blockIdx.x;
    int tid = threadIdx.x;
    if (bx < 432) {
        int idx = bx * 256 + tid;
        if (idx < 36864) d2b[idx] = b2[(idx / 576) & 31];
        else d1b[idx - 36864] = b1[((idx - 36864) / HW) & 15];
        return;
    }
    if (bx < 504) {
        int sub = bx - 432;
        int arr = sub / 36;
        int ni = (sub % 36) / 9, pt = sub % 9;
        int plane = 2 + (ni & 1) + 4 * (ni >> 1);
        const float* src = (arr == 0 ? x1 : x2) + (size_t)plane * HW;
        emb_body(src, arr, ni, pt, ew, eb, hl, nrm, wl, tid, 256);
        return;
    }
    if (bx < 576) {
        int i = (bx - 504) * 256 + tid;
        initbuf[i] = 0x7F800000u;
        return;
    }
    // ---- enc1pool (32 blocks) ----
    int co = (bx - 576) & 15, n = (bx - 576) >> 4;
    for (int i = tid; i < 27; i += 256) wl1[(i / 9) * 12 + (i % 9)] = e1w[(co * 3) * 9 + i];
    stage_rows(x3 + (size_t)n * 3 * HW, lds, 3, HW, 48, 48, -1, 50, tid, 256, false);
    float bv = e1b[co];
    for (int o = 0; o < 3; ++o) {
        int po = o * 256 + tid;
        if (po >= 576) break;
        int py = po / 24, px = po % 24;
        float s[2][2] = {{bv, bv}, {bv, bv}};
        for (int ci = 0; ci < 3; ++ci) {
            const float* chp = lds + ci * 2600;
            float c[4][6];
            #pragma unroll
            for (int rr = 0; rr < 4; ++rr) {
                const float2* pr = (const float2*)(chp + (2 * py + rr) * 52);
                #pragma unroll
                for (int k = 0; k < 3; ++k) { float2 t = pr[px + k]; c[rr][2 * k] = t.x; c[rr][2 * k + 1] = t.y; }
            }
            LOAD_W9(wl1, ci)
            #pragma unroll
            for (int dy = 0; dy < 3; ++dy)
                #pragma unroll
                for (int dx = 0; dx < 3; ++dx) {
                    float wv = w9[dy * 3 + dx];
                    #pragma unroll
                    for (int yy = 0; yy < 2; ++yy)
                        #pragma unroll
                        for (int xx = 0; xx < 2; ++xx)
                            s[yy][xx] = fmaf(c[yy + dy][xx + dx + 1], wv, s[yy][xx]);
                }
        }
        float* ob = e1u + (size_t)(n * 16 + co) * HW;
        float mx = -INFINITY;
        #pragma unroll
        for (int yy = 0; yy < 2; ++yy)
            #pragma unroll
            for (int xx = 0; xx < 2; ++xx) {
                float v = fmaxf(s[yy][xx], 0.f);
                ob[(2 * py + yy) * 48 + 2 * px + xx] = v;
                mx = fmaxf(mx, v);
            }
        p1[(size_t)(n * 16 + co) * 576 + py * 24 + px] = mx;
    }
}

// ---- enc2pool (r4-verified). grid 64, 192 threads ----
__global__ __launch_bounds__(192) void k_enc2pool(const float* __restrict__ p1, const float* __restrict__ w,
                                                  const float* __restrict__ b, float* __restrict__ e2,
                                                  float* __restrict__ p2) {
    int co = blockIdx.x & 31, n = blockIdx.x >> 5;
    int tid = threadIdx.x;
    __shared__ __align__(16) float lds[16 * 26 * 28];
    __shared__ __align__(16) float wl[192];
    for (int i = tid; i < 144; i += 192) wl[(i / 9) * 12 + (i % 9)] = w[(co * 16) * 9 + i];
    stage_rows(p1 + (size_t)n * 16 * 576, lds, 16, 576, 24, 24, -1, 26, tid, 192, false);
    if (tid < 144) {
        int py = tid / 12, px = tid % 12;
        float bv = b[co];
        float s[2][2] = {{bv, bv}, {bv, bv}};
        for (int ci = 0; ci < 16; ++ci) {
            const float* chp = lds + ci * 728;
            float c[4][6];
            #pragma unroll
            for (int rr = 0; rr < 4; ++rr) {
                const float2* pr = (const float2*)(chp + (2 * py + rr) * 28);
                #pragma unroll
                for (int k = 0; k < 3; ++k) { float2 t = pr[px + k]; c[rr][2 * k] = t.x; c[rr][2 * k + 1] = t.y; }
            }
            LOAD_W9(wl, ci)
            #pragma unroll
            for (int dy = 0; dy < 3; ++dy)
                #pragma unroll
                for (int dx = 0; dx < 3; ++dx) {
                    float wv = w9[dy * 3 + dx];
                    #pragma unroll
                    for (int yy = 0; yy < 2; ++yy)
                        #pragma unroll
                        for (int xx = 0; xx < 2; ++xx)
                            s[yy][xx] = fmaf(c[yy + dy][xx + dx + 1], wv, s[yy][xx]);
                }
        }
        float* ob = e2 + (size_t)(n * 32 + co) * 576;
        float mx = -INFINITY;
        #pragma unroll
        for (int yy = 0; yy < 2; ++yy)
            #pragma unroll
            for (int xx = 0; xx < 2; ++xx) {
                float v = fmaxf(s[yy][xx], 0.f);
                ob[(2 * py + yy) * 24 + 2 * px + xx] = v;
                mx = fmaxf(mx, v);
            }
        p2[(size_t)(n * 32 + co) * 144 + py * 12 + px] = mx;
    }
}

// ---- bottleneck (r4-verified). grid 128, 192 threads ----
__global__ __launch_bounds__(192) void k_bott(const float* __restrict__ p2, const float* __restrict__ w,
                                              const float* __restrict__ b, float* __restrict__ bt) {
    int co = blockIdx.x & 63, n = blockIdx.x >> 6;
    int tid = threadIdx.x;
    __shared__ __align__(16) float lds[32 * 14 * 16];
    __shared__ __align__(16) float wl[384];
    for (int i = tid; i < 288; i += 192) wl[(i / 9) * 12 + (i % 9)] = w[(co * 32) * 9 + i];
    stage_rows(p2 + (size_t)n * 32 * 144, lds, 32, 144, 12, 12, -1, 14, tid, 192, false);
    if (tid < 144) {
        int y = tid / 12, x = tid % 12;
        float acc = b[co];
        for (int ci = 0; ci < 32; ++ci) {
            const float* chp = lds + ci * 224;
            LOAD_W9(wl, ci)
            #pragma unroll
            for (int dy = 0; dy < 3; ++dy)
                #pragma unroll
                for (int dx = 0; dx < 3; ++dx)
                    acc = fmaf(chp[(y + dy) * 16 + x + dx + 1], w9[dy * 3 + dx], acc);
        }
        bt[(size_t)(n * 64 + co) * 144 + y * 12 + x] = fmaxf(acc, 0.f);
    }
}

// ---- dec2 partial (r4-verified). grid 256, 192 threads ----
__global__ __launch_bounds__(192) void k_dec2p(const float* __restrict__ bt, const float* __restrict__ e2,
                                               const float* __restrict__ w, float* __restrict__ d2b) {
    int bx = blockIdx.x;
    int chunk = bx & 3, co = (bx >> 2) & 31, n = bx >> 7;
    int cib = chunk * 24;
    int nA = max(0, min(24, 64 - cib));
    int nB = 24 - nA;
    int tid = threadIdx.x;
    __shared__ __align__(16) float lds[24 * 26 * 28];
    __shared__ __align__(16) float wl[288];
    for (int i = tid; i < 216; i += 192) wl[(i / 9) * 12 + (i % 9)] = w[((size_t)co * 96 + cib) * 9 + i];
    stage_rows(bt + ((size_t)n * 64 + cib) * 144, lds, nA, 144, 12, 12, -1, 14, tid, 192, false);
    float* ldsB = lds + nA * 224;
    int e2c = max(0, cib + nA - 64);
    stage_rows(e2 + ((size_t)n * 32 + e2c) * 576, ldsB, nB, 576, 24, 24, -1, 26, tid, 192, false);
    if (tid < 144) {
        int y = tid / 6, qx = tid % 6;
        float acc[4] = {0.f, 0.f, 0.f, 0.f};
        int r0 = ((y - 1) >> 1) + 1;
        int yodd = y & 1;
        for (int ci = 0; ci < nA; ++ci) {
            const float* chp = lds + ci * 224;
            const float2* p0 = (const float2*)(chp + r0 * 16);
            const float2* p1 = (const float2*)(chp + (r0 + 1) * 16);
            float a0[6], a1[6], am[6];
            #pragma unroll
            for (int k = 0; k < 3; ++k) {
                float2 t0 = p0[qx + k], t1 = p1[qx + k];
                a0[2 * k] = t0.x; a0[2 * k + 1] = t0.y;
                a1[2 * k] = t1.x; a1[2 * k + 1] = t1.y;
            }
            #pragma unroll
            for (int k = 0; k < 6; ++k) am[k] = yodd ? a0[k] : a1[k];
            LOAD_W9(wl, ci)
            #pragma unroll
            for (int dy = 0; dy < 3; ++dy) {
                const float* rr = (dy == 0) ? a0 : (dy == 1 ? am : a1);
                #pragma unroll
                for (int dx = 0; dx < 3; ++dx) {
                    float wv = w9[dy * 3 + dx];
                    #pragma unroll
                    for (int j = 0; j < 4; ++j)
                        acc[j] = fmaf(rr[((j + dx - 1) >> 1) + 2], wv, acc[j]);
                }
            }
        }
        for (int ci = 0; ci < nB; ++ci) {
            const float* chp = ldsB + ci * 728;
            float bvv[3][8];
            #pragma unroll
            for (int r = 0; r < 3; ++r) {
                const float2* pr = (const float2*)(chp + (y + r) * 28);
                #pragma unroll
                for (int k = 0; k < 4; ++k) { float2 t = pr[2 * qx + k]; bvv[r][2 * k] = t.x; bvv[r][2 * k + 1] = t.y; }
            }
            LOAD_W9(wl, nA + ci)
            #pragma unroll
            for (int dy = 0; dy < 3; ++dy)
                #pragma unroll
                for (int dx = 0; dx < 3; ++dx) {
                    float wv = w9[dy * 3 + dx];
                    #pragma unroll
                    for (int j = 0; j < 4; ++j)
                        acc[j] = fmaf(bvv[dy][j + dx + 1], wv, acc[j]);
                }
        }
        float* op = d2b + ((size_t)(n * 32 + co)) * 576 + y * 24 + qx * 4;
        #pragma unroll
        for (int j = 0; j < 4; ++j) atomicAdd(op + j, acc[j]);
    }
}

// ---- dec1 partial (r4-verified). grid 384, 192 threads ----
__global__ __launch_bounds__(192) void k_dec1p(const float* __restrict__ d2b, const float* __restrict__ e1u,
                                               const float* __restrict__ w, float* __restrict__ d1b) {
    int bx = blockIdx.x;
    int strip = bx % 3;
    int chunk = (bx / 3) & 3;
    int co = (bx / 12) & 15;
    int n = bx / 192;
    int cib = chunk * 12;
    int nA = max(0, min(12, 32 - cib));
    int nB = 12 - nA;
    int y0 = strip * 16;
    int yhlo = (y0 - 1) >> 1;
    int tid = threadIdx.x;
    __shared__ __align__(16) float lds[12 * 18 * 52];
    __shared__ __align__(16) float wl[144];
    for (int i = tid; i < 108; i += 192) wl[(i / 9) * 12 + (i % 9)] = w[((size_t)co * 48 + cib) * 9 + i];
    stage_rows(d2b + ((size_t)n * 32 + cib) * 576, lds, nA, 576, 24, 24, yhlo, 10, tid, 192, true);
    float* ldsB = lds + nA * 280;
    int e1c = max(0, cib + nA - 32);
    stage_rows(e1u + ((size_t)n * 16 + e1c) * HW, ldsB, nB, HW, 48, 48, y0 - 1, 18, tid, 192, false);
    {
        int yl = tid / 12, qx = tid % 12;
        int y = y0 + yl;
        float acc[4] = {0.f, 0.f, 0.f, 0.f};
        int r0 = ((y - 1) >> 1) - yhlo;
        int yodd = y & 1;
        for (int ci = 0; ci < nA; ++ci) {
            const float* chp = lds + ci * 280;
            const float2* p0 = (const float2*)(chp + r0 * 28);
            const float2* p1 = (const float2*)(chp + (r0 + 1) * 28);
            float a0[6], a1[6], am[6];
            #pragma unroll
            for (int k = 0; k < 3; ++k) {
                float2 t0 = p0[qx + k], t1 = p1[qx + k];
                a0[2 * k] = t0.x; a0[2 * k + 1] = t0.y;
                a1[2 * k] = t1.x; a1[2 * k + 1] = t1.y;
            }
            #pragma unroll
            for (int k = 0; k < 6; ++k) am[k] = yodd ? a0[k] : a1[k];
            LOAD_W9(wl, ci)
            #pragma unroll
            for (int dy = 0; dy < 3; ++dy) {
                const float* rr = (dy == 0) ? a0 : (dy == 1 ? am : a1);
                #pragma unroll
                for (int dx = 0; dx < 3; ++dx) {
                    float wv = w9[dy * 3 + dx];
                    #pragma unroll
                    for (int j = 0; j < 4; ++j)
                        acc[j] = fmaf(rr[((j + dx - 1) >> 1) + 2], wv, acc[j]);
                }
            }
        }
        for (int ci = 0; ci < nB; ++ci) {
            const float* chp = ldsB + ci * 936;
            float bvv[3][8];
            #pragma unroll
            for (int r = 0; r < 3; ++r) {
                const float2* pr = (const float2*)(chp + (yl + r) * 52);
                #pragma unroll
                for (int k = 0; k < 4; ++k) { float2 t = pr[2 * qx + k]; bvv[r][2 * k] = t.x; bvv[r][2 * k + 1] = t.y; }
            }
            LOAD_W9(wl, nA + ci)
            #pragma unroll
            for (int dy = 0; dy < 3; ++dy)
                #pragma unroll
                for (int dx = 0; dx < 3; ++dx) {
                    float wv = w9[dy * 3 + dx];
                    #pragma unroll
                    for (int j = 0; j < 4; ++j)
                        acc[j] = fmaf(bvv[dy][j + dx + 1], wv, acc[j]);
                }
        }
        float* op = d1b + ((size_t)(n * 16 + co)) * HW + y * 48 + qx * 4;
        #pragma unroll
        for (int j = 0; j < 4; ++j) atomicAdd(op + j, acc[j]);
    }
}

// ================= k_matchx: match with INLINE q-side embedding from d1b =================
// blocks [0,864): match, ps split 6-ways (P slice 384, NPC 12) -> 3.66 blocks/CU average,
//   3 co-resident (LDS 41.9 KB) overlap each other's vmcnt/barrier stalls (r8 mechanism).
// blocks [864,936): out1x1 -> x3s (concurrent, independent)
#define NPC 12
__global__ __launch_bounds__(256, 3) void k_matchx(
        const unsigned short* __restrict__ hl, const float* __restrict__ nrm,
        const float* __restrict__ d1b, const float* __restrict__ ow,
        const float* __restrict__ obias, const float* __restrict__ ew,
        const float* __restrict__ eb,
        unsigned* __restrict__ gmd, unsigned* __restrict__ lmd,
        float* __restrict__ x3s) {
    int tid = threadIdx.x;
    if (blockIdx.x >= 864) {          // ---- out1x1 -> x3s (72 blocks) ----
        int idx = (blockIdx.x - 864) * 256 + tid;
        int q = idx % HW;
        int co = (idx / HW) & 3;
        int n = idx / 9216;
        float acc = obias[co];
        #pragma unroll
        for (int ci = 0; ci < 16; ++ci)
            acc = fmaf(fmaxf(d1b[((size_t)(n * 16 + ci)) * HW + q], 0.f), ow[co * 16 + ci], acc);
        x3s[((size_t)(n * 4 + co)) * HW + q] = acc;
        return;
    }
    int bx = blockIdx.x;
    int l = (bx & 7) * 108 + (bx >> 3);       // bijective: 864 = 8*108; mn pinned per XCD
    int ps = l % 6;
    int qt = (l / 6) % 18;
    int mn = l / 108;
    int n = mn & 3;
    int m = mn >> 2;

    const unsigned short* refhl = hl + ((size_t)(m * 4 + n)) * HW * 256;
    const float* na = nrm + (size_t)(m * 4 + n) * HW;
    unsigned* outd = (m == 0 ? gmd : lmd) + (size_t)n * HW;

    int qbase = qt * 128;
    int pbase = ps * 384;

    __shared__ __align__(16) float smem[10392];
    unsigned short* refl0 = (unsigned short*)smem;   // [0, 8192) floats: 2 x 16 KB (main loop)
    unsigned short* refl1 = refl0 + 32 * 256;
    float* dtile = smem;                             // ALIASES refl: 288 pix x 17 = 4896 floats, prologue only
    float* nal = smem + 8192;                        // [8192, 8576): 384 p-norms
    float* wl  = smem + 8960;                        // [8960, 10260)
    float* nbl = smem + 10260;                       // [10260, 10388)

    int wave = tid >> 6;
    int lane = tid & 63;
    int lr = lane >> 5;
    int lc = lane & 31;

    // ---- cooperative staging: na (P-norms), emb weights, d1b tile ----
    if (tid < 96) *(float4*)&nal[tid * 4] = *(const float4*)(na + pbase + tid * 4);
    for (int i = tid; i < 900; i += 256) wl[(i / 9) * 12 + (i % 9)] = ew[i];
    for (int i = tid; i < 100; i += 256) wl[1200 + i] = eb[i];

    int b_ = n >> 1;               // batch
    int co_ = 2 + (n & 1);         // out-channel (classes 2,3 only)
    const float* dp = d1b + (size_t)b_ * 16 * HW;
    int y0t = qbase / 48 - 1;      // first staged image row (may be -1)
    for (int i = tid; i < 1152; i += 256) {    // 16 ci x 72 pix4-groups
        int ci = i / 72;
        int pp = (i % 72) * 4;                 // pixel-local 0..284 (row-aligned: 48%4==0)
        int yy = y0t + pp / 48;
        int xx = pp % 48;
        float4 v = make_float4(0.f, 0.f, 0.f, 0.f);
        if (yy >= 0 && yy < 48) {
            v = *(const float4*)(dp + (size_t)ci * HW + yy * 48 + xx);
            v.x = fmaxf(v.x, 0.f); v.y = fmaxf(v.y, 0.f);
            v.z = fmaxf(v.z, 0.f); v.w = fmaxf(v.w, 0.f);
        }
        dtile[(pp + 0) * 17 + ci] = v.x;
        dtile[(pp + 1) * 17 + ci] = v.y;
        dtile[(pp + 2) * 17 + ci] = v.z;
        dtile[(pp + 3) * 17 + ci] = v.w;
    }
    __syncthreads();

    // ---- inline q-side embedding: each lane computes exactly its MFMA fragment slice ----
    float owr[16];
    #pragma unroll
    for (int k = 0; k < 16; ++k) owr[k] = ow[co_ * 16 + k];
    float obv = obias[co_];

    short8 ahi[2][4], alo[2][4];
    int eb0 = (lane >> 4) * 8;
    #pragma unroll
    for (int j = 0; j < 2; ++j) {
        int rloc = wave * 32 + j * 16 + (lane & 15);
        int r = qbase + rloc;
        int x = r % 48, y = r / 48;
        float p9[9];
        #pragma unroll
        for (int ky = 0; ky < 3; ++ky)
            #pragma unroll
            for (int kx = 0; kx < 3; ++kx) {
                int yy = y + ky - 1, xx = x + kx - 1;
                float v = 0.f;
                if (yy >= 0 && yy < 48 && xx >= 0 && xx < 48) {
                    v = obv;
                    const float* dpix = &dtile[((yy - y0t) * 48 + xx) * 17];
                    #pragma unroll
                    for (int ci = 0; ci < 16; ++ci) v = fmaf(dpix[ci], owr[ci], v);
                }
                p9[ky * 3 + kx] = v;
            }
        float nsum = 0.f;
        #pragma unroll
        for (int ks = 0; ks < 4; ++ks) {
            short8 vh, vlo;
            #pragma unroll
            for (int t = 0; t < 8; ++t) {
                int e = ks * 32 + eb0 + t;
                float v = 0.f;
                if (e < 100) {
                    v = wl[1200 + e];
                    #pragma unroll
                    for (int k = 0; k < 9; ++k) v = fmaf(p9[k], wl[e * 12 + k], v);
                    nsum = fmaf(v, v, nsum);
                }
                unsigned bits = __float_as_uint(v);
                vh[t] = (short)(bits >> 16);
                float lo = v - __uint_as_float(bits & 0xFFFF0000u);
                vlo[t] = (short)(__float_as_uint(lo) >> 16);
            }
            ahi[j][ks] = vh;
            alo[j][ks] = vlo;
        }
        // full row norm: lanes {L, L+16, L+32, L+48} hold disjoint 32-dim slices of row rloc
        nsum += __shfl_xor(nsum, 16, 64);
        nsum += __shfl_xor(nsum, 32, 64);
        if ((lane >> 4) == 0) nbl[rloc] = nsum;
    }
    __syncthreads();   // dtile reads done -> refl region may be overwritten

    // ---- prologue: stage ref chunk 0 ----
    {
        const unsigned short* gb = refhl + (size_t)pbase * 256;
        #pragma unroll
        for (int t = 0; t < 4; ++t) {
            int i = wave * 4 + t;
            int r = 2 * i + lr;
            gll16(gb + (size_t)r * 256 + (lc ^ (r & 7)) * 8, refl0 + i * 512);
        }
    }
    asm volatile("s_waitcnt lgkmcnt(0)" ::: "memory");

    float dmin[2][4];
    #pragma unroll
    for (int j = 0; j < 2; ++j)
        #pragma unroll
        for (int r = 0; r < 4; ++r) dmin[j][r] = INFINITY;

    for (int pc = 0; pc < NPC; ++pc) {
        unsigned short* cur = (pc & 1) ? refl1 : refl0;
        unsigned short* nxt = (pc & 1) ? refl0 : refl1;
        if (pc + 1 < NPC) {
            const unsigned short* gb = refhl + (size_t)(pbase + (pc + 1) * 32) * 256;
            #pragma unroll
            for (int t = 0; t < 4; ++t) {
                int i = wave * 4 + t;
                int r = 2 * i + lr;
                gll16(gb + (size_t)r * 256 + (lc ^ (r & 7)) * 8, nxt + i * 512);
            }
            asm volatile("s_waitcnt vmcnt(4)" ::: "memory");
        } else {
            asm volatile("s_waitcnt vmcnt(0)" ::: "memory");
        }
        __builtin_amdgcn_s_barrier();

        short8 bhi[2][4], blo[2][4];
        #pragma unroll
        for (int ptile = 0; ptile < 2; ++ptile) {
            int r = ptile * 16 + (lane & 15);
            #pragma unroll
            for (int ks = 0; ks < 4; ++ks) {
                int cg = ks * 4 + (lane >> 4);
                const char* p = (const char*)cur + r * 512 + ((cg ^ (r & 7)) << 4);
                bhi[ptile][ks] = *(const short8*)p;
                blo[ptile][ks] = *(const short8*)(p + 256);
            }
        }

        f32x4 acc[2][2];
        #pragma unroll
        for (int ptile = 0; ptile < 2; ++ptile)
            #pragma unroll
            for (int j = 0; j < 2; ++j) acc[ptile][j] = (f32x4){0.f, 0.f, 0.f, 0.f};

        #pragma unroll
        for (int ks = 0; ks < 4; ++ks) {
            #pragma unroll
            for (int ptile = 0; ptile < 2; ++ptile)
                #pragma unroll
                for (int j = 0; j < 2; ++j)
                    acc[ptile][j] = __builtin_amdgcn_mfma_f32_16x16x32_bf16(
                        ahi[j][ks], bhi[ptile][ks], acc[ptile][j], 0, 0, 0);
            #pragma unroll
            for (int ptile = 0; ptile < 2; ++ptile)
                #pragma unroll
                for (int j = 0; j < 2; ++j)
                    acc[ptile][j] = __builtin_amdgcn_mfma_f32_16x16x32_bf16(
                        ahi[j][ks], blo[ptile][ks], acc[ptile][j], 0, 0, 0);
            #pragma unroll
            for (int ptile = 0; ptile < 2; ++ptile)
                #pragma unroll
                for (int j = 0; j < 2; ++j)
                    acc[ptile][j] = __builtin_amdgcn_mfma_f32_16x16x32_bf16(
                        alo[j][ks], bhi[ptile][ks], acc[ptile][j], 0, 0, 0);
        }

        #pragma unroll
        for (int ptile = 0; ptile < 2; ++ptile) {
            float nav = nal[pc * 32 + ptile * 16 + (lane & 15)];
            #pragma unroll
            for (int j = 0; j < 2; ++j)
                #pragma unroll
                for (int r = 0; r < 4; ++r)
                    dmin[j][r] = fminf(dmin[j][r], fmaf(-2.f, acc[ptile][j][r], nav));
        }
        __builtin_amdgcn_s_barrier();
    }

    #pragma unroll
    for (int j = 0; j < 2; ++j)
        #pragma unroll
        for (int r = 0; r < 4; ++r) {
            float v = dmin[j][r];
            v = fminf(v, __shfl_xor(v, 1, 64));
            v = fminf(v, __shfl_xor(v, 2, 64));
            v = fminf(v, __shfl_xor(v, 4, 64));
            v = fminf(v, __shfl_xor(v, 8, 64));
            if ((lane & 15) == 0) {
                int qloc = wave * 32 + j * 16 + 4 * (lane >> 4) + r;
                float d2 = fmaxf(v + nbl[qloc], 0.f);
                atomicMin(&outd[qbase + qloc], __float_as_uint(d2));
            }
        }
}

// ---- final dsh conv (r4-verified) ----
__global__ void k_final(const float* __restrict__ x3s, const unsigned* __restrict__ gmd,
                        const unsigned* __restrict__ lmd, const float* __restrict__ x2,
                        const float* __restrict__ dshw, const float* __restrict__ dshb,
                        float* __restrict__ out) {
    int idx = blockIdx.x * THREADS + threadIdx.x;
    if (idx >= 9216) return;
    int q = idx % HW, ni = idx / HW;
    int n = 2 + (ni & 1) + 4 * (ni >> 1);
    int b = ni >> 1;
    int x = q % 48, y = q / 48;
    float acc = dshb[0];
    for (int c = 0; c < 7; ++c) {
        const float* wp = dshw + c * 9;
        #pragma unroll
        for (int ky = 0; ky < 3; ++ky) {
            int yy = y + ky - 1;
            if (yy < 0 || yy >= 48) continue;
            #pragma unroll
            for (int kx = 0; kx < 3; ++kx) {
                int xx = x + kx - 1;
                if (xx < 0 || xx >= 48) continue;
                float v;
                if (c < 4) v = x3s[(size_t)(b * 4 + c) * HW + yy * 48 + xx];
                else if (c == 4) {
                    float d2 = __uint_as_float(gmd[(size_t)ni * HW + yy * 48 + xx]);
                    v = 1.f - 2.f / (1.f + expf(d2));
                } else if (c == 5) {
                    float d2 = __uint_as_float(lmd[(size_t)ni * HW + yy * 48 + xx]);
                    v = 1.f - 2.f / (1.f + expf(d2));
                } else v = x2[(size_t)n * HW + yy * 48 + xx];
                acc = fmaf(v, wp[ky * 3 + kx], acc);
            }
        }
    }
    out[idx] = acc;
}

extern "C" void kernel_launch(void* const* d_in, const int* in_sizes, int n_in,
                              void* d_out, int out_size, void* d_ws, size_t ws_size,
                              hipStream_t stream) {
    const float* x1     = (const float*)d_in[0];
    const float* x2     = (const float*)d_in[1];
    const float* x3     = (const float*)d_in[2];
    const float* enc1_w = (const float*)d_in[3];
    const float* enc1_b = (const float*)d_in[4];
    const float* enc2_w = (const float*)d_in[5];
    const float* enc2_b = (const float*)d_in[6];
    const float* bott_w = (const float*)d_in[7];
    const float* bott_b = (const float*)d_in[8];
    const float* dec2_w = (const float*)d_in[9];
    const float* dec2_b = (const float*)d_in[10];
    const float* dec1_w = (const float*)d_in[11];
    const float* dec1_b = (const float*)d_in[12];
    const float* out_w  = (const float*)d_in[13];
    const float* out_b  = (const float*)d_in[14];
    const float* emb_w  = (const float*)d_in[15];
    const float* emb_b  = (const float*)d_in[16];
    const float* dsh_w  = (const float*)d_in[17];
    const float* dsh_b  = (const float*)d_in[18];

    float* w = (float*)d_ws;
    float* e1u  = w;                   // [0, 73728)
    float* p1   = w + 73728;           // [73728, 92160)
    float* e2   = w + 92160;           // [92160, 129024)
    float* p2   = w + 129024;          // [129024, 138240)
    float* bt   = w + 138240;          // [138240, 156672)
    float* d2b  = w + 156672;          // [156672, 193536)
    float* d1b  = w + 193536;          // [193536, 267264)
    float* x3s  = w + 267264;          // [267264, 285696)
    float* nrm  = w + 285696;          // [285696, 313344)
    unsigned* gmd = (unsigned*)(w + 313344);   // [313344, 322560)
    unsigned* lmd = (unsigned*)(w + 322560);   // [322560, 331776)
    unsigned short* hl = (unsigned short*)(w + 331776);  // arr0/arr1 used only

    k_pre<<<dim3(608), dim3(256), 0, stream>>>(d2b, d1b, dec2_b, dec1_b, x1, x2, emb_w, emb_b,
                                               hl, nrm, gmd, x3, enc1_w, enc1_b, e1u, p1);
    k_enc2pool<<<dim3(64), dim3(192), 0, stream>>>(p1, enc2_w, enc2_b, e2, p2);
    k_bott<<<dim3(128), dim3(192), 0, stream>>>(p2, bott_w, bott_b, bt);
    k_dec2p<<<dim3(256), dim3(192), 0, stream>>>(bt, e2, dec2_w, d2b);
    k_dec1p<<<dim3(384), dim3(192), 0, stream>>>(d2b, e1u, dec1_w, d1b);
    k_matchx<<<dim3(936), dim3(256), 0, stream>>>(hl, nrm, d1b, out_w, out_b, emb_w, emb_b,
                                                  gmd, lmd, x3s);
    k_final<<<dim3(36), dim3(THREADS), 0, stream>>>(x3s, gmd, lmd, x2, dsh_w, dsh_b, (float*)d_out);
}

// Round 15
// 122.812 us; speedup vs baseline: 1.0743x; 1.0743x over previous
//
#include <hip/hip_runtime.h>
#include <math.h>

#define THREADS 256
#define HW 2304

typedef __attribute__((ext_vector_type(8))) short short8;
typedef __attribute__((ext_vector_type(4))) float f32x4;
typedef __attribute__((ext_vector_type(8))) unsigned short us8;

typedef const __attribute__((address_space(1))) void* gas_p;
typedef __attribute__((address_space(3))) void* las_p;

__device__ __forceinline__ void gll16(const void* g, const void* l) {
    __builtin_amdgcn_global_load_lds((gas_p)g, (las_p)l, 16, 0, 0);
}

// ---- generic LDS staging: zero-padded halo rows ----
__device__ __forceinline__ void stage_rows(const float* __restrict__ src, float* __restrict__ dst,
                                           int nch, int chStride, int H, int W,
                                           int rlo, int rcount, int tid, int nthr, bool relu) {
    int rowfl = W + 4;
    int total = nch * rcount * rowfl;
    float4 z = make_float4(0.f, 0.f, 0.f, 0.f);
    for (int i = tid; i * 4 < total; i += nthr) ((float4*)dst)[i] = z;
    __syncthreads();
    int w2 = W >> 1;
    int m = nch * rcount * w2;
    for (int i = tid; i < m; i += nthr) {
        int c2 = i % w2;
        int rr = (i / w2) % rcount;
        int ch = i / (w2 * rcount);
        int srow = rlo + rr;
        if (srow < 0 || srow >= H) continue;
        float2 v = *(const float2*)(src + (size_t)ch * chStride + srow * W + 2 * c2);
        if (relu) { v.x = fmaxf(v.x, 0.f); v.y = fmaxf(v.y, 0.f); }
        *(float2*)(dst + (size_t)ch * rcount * rowfl + rr * rowfl + 2 + 2 * c2) = v;
    }
    __syncthreads();
}

#define LOAD_W9(wlbase, ci)                                        \
    const float4* wp4 = (const float4*)((wlbase) + (ci) * 12);     \
    float4 wa = wp4[0], wb = wp4[1], wc = wp4[2];                  \
    const float w9[9] = {wa.x, wa.y, wa.z, wa.w, wb.x, wb.y, wb.z, wb.w, wc.x};

// ---- embedding conv body (global src) + norm + bf16 hi/lo split ----
__device__ __forceinline__ void emb_body(const float* __restrict__ src, int arr, int ni, int pt,
                                         const float* __restrict__ ew, const float* __restrict__ eb,
                                         unsigned short* __restrict__ hl, float* __restrict__ nrm,
                                         float* wl, int tid, int nthr) {
    for (int i = tid; i < 900; i += nthr) wl[(i / 9) * 12 + (i % 9)] = ew[i];
    for (int i = tid; i < 100; i += nthr) wl[1200 + i] = eb[i];
    __syncthreads();

    int pix = pt * 256 + tid;
    int x = pix % 48, y = pix / 48;
    float p9[9];
    #pragma unroll
    for (int ky = 0; ky < 3; ++ky)
        #pragma unroll
        for (int kx = 0; kx < 3; ++kx) {
            int yy = y + ky - 1, xx = x + kx - 1;
            p9[ky * 3 + kx] = (yy >= 0 && yy < 48 && xx >= 0 && xx < 48) ? src[yy * 48 + xx] : 0.f;
        }

    float nsum = 0.f;
    char* rowp = (char*)(hl + (((size_t)(arr * 4 + ni)) * HW + pix) * 256);
    for (int g = 0; g < 16; ++g) {
        us8 vh, vl;
        #pragma unroll
        for (int j = 0; j < 8; ++j) {
            int e = g * 8 + j;
            float v = 0.f;
            if (e < 100) {
                v = wl[1200 + e];
                #pragma unroll
                for (int k = 0; k < 9; ++k) v = fmaf(p9[k], wl[e * 12 + k], v);
                nsum = fmaf(v, v, nsum);
            }
            unsigned bits = __float_as_uint(v);
            vh[j] = (unsigned short)(bits >> 16);
            float lo = v - __uint_as_float(bits & 0xFFFF0000u);
            vl[j] = (unsigned short)(__float_as_uint(lo) >> 16);
        }
        *(us8*)(rowp + g * 16) = vh;
        *(us8*)(rowp + 256 + g * 16) = vl;
    }
    nrm[(size_t)(arr * 4 + ni) * HW + pix] = nsum;
}

// ---- k_pre (r4-verified): bias-init, embprep(x1,x2), inf-init, enc1pool. grid 608 ----
__global__ __launch_bounds__(256) void k_pre(
        float* __restrict__ d2b, float* __restrict__ d1b,
        const float* __restrict__ b2, const float* __restrict__ b1,
        const float* __restrict__ x1, const float* __restrict__ x2,
        const float* __restrict__ ew, const float* __restrict__ eb,
        unsigned short* __restrict__ hl, float* __restrict__ nrm,
        unsigned* __restrict__ initbuf,
        const float* __restrict__ x3, const float* __restrict__ e1w,
        const float* __restrict__ e1b, float* __restrict__ e1u, float* __restrict__ p1) {
    __shared__ __align__(16) float lds[3 * 50 * 52];
    __shared__ __align__(16) float wl1[48];
    __shared__ float wl[1300];
    int bx = blockIdx.x;
    int tid = threadIdx.x;
    if (bx < 432) {
        int idx = bx * 256 + tid;
        if (idx < 36864) d2b[idx] = b2[(idx / 576) & 31];
        else d1b[idx - 36864] = b1[((idx - 36864) / HW) & 15];
        return;
    }
    if (bx < 504) {
        int sub = bx - 432;
        int arr = sub / 36;
        int ni = (sub % 36) / 9, pt = sub % 9;
        int plane = 2 + (ni & 1) + 4 * (ni >> 1);
        const float* src = (arr == 0 ? x1 : x2) + (size_t)plane * HW;
        emb_body(src, arr, ni, pt, ew, eb, hl, nrm, wl, tid, 256);
        return;
    }
    if (bx < 576) {
        int i = (bx - 504) * 256 + tid;
        initbuf[i] = 0x7F800000u;
        return;
    }
    // ---- enc1pool (32 blocks) ----
    int co = (bx - 576) & 15, n = (bx - 576) >> 4;
    for (int i = tid; i < 27; i += 256) wl1[(i / 9) * 12 + (i % 9)] = e1w[(co * 3) * 9 + i];
    stage_rows(x3 + (size_t)n * 3 * HW, lds, 3, HW, 48, 48, -1, 50, tid, 256, false);
    float bv = e1b[co];
    for (int o = 0; o < 3; ++o) {
        int po = o * 256 + tid;
        if (po >= 576) break;
        int py = po / 24, px = po % 24;
        float s[2][2] = {{bv, bv}, {bv, bv}};
        for (int ci = 0; ci < 3; ++ci) {
            const float* chp = lds + ci * 2600;
            float c[4][6];
            #pragma unroll
            for (int rr = 0; rr < 4; ++rr) {
                const float2* pr = (const float2*)(chp + (2 * py + rr) * 52);
                #pragma unroll
                for (int k = 0; k < 3; ++k) { float2 t = pr[px + k]; c[rr][2 * k] = t.x; c[rr][2 * k + 1] = t.y; }
            }
            LOAD_W9(wl1, ci)
            #pragma unroll
            for (int dy = 0; dy < 3; ++dy)
                #pragma unroll
                for (int dx = 0; dx < 3; ++dx) {
                    float wv = w9[dy * 3 + dx];
                    #pragma unroll
                    for (int yy = 0; yy < 2; ++yy)
                        #pragma unroll
                        for (int xx = 0; xx < 2; ++xx)
                            s[yy][xx] = fmaf(c[yy + dy][xx + dx + 1], wv, s[yy][xx]);
                }
        }
        float* ob = e1u + (size_t)(n * 16 + co) * HW;
        float mx = -INFINITY;
        #pragma unroll
        for (int yy = 0; yy < 2; ++yy)
            #pragma unroll
            for (int xx = 0; xx < 2; ++xx) {
                float v = fmaxf(s[yy][xx], 0.f);
                ob[(2 * py + yy) * 48 + 2 * px + xx] = v;
                mx = fmaxf(mx, v);
            }
        p1[(size_t)(n * 16 + co) * 576 + py * 24 + px] = mx;
    }
}

// ---- enc2pool (r4-verified). grid 64, 192 threads ----
__global__ __launch_bounds__(192) void k_enc2pool(const float* __restrict__ p1, const float* __restrict__ w,
                                                  const float* __restrict__ b, float* __restrict__ e2,
                                                  float* __restrict__ p2) {
    int co = blockIdx.x & 31, n = blockIdx.x >> 5;
    int tid = threadIdx.x;
    __shared__ __align__(16) float lds[16 * 26 * 28];
    __shared__ __align__(16) float wl[192];
    for (int i = tid; i < 144; i += 192) wl[(i / 9) * 12 + (i % 9)] = w[(co * 16) * 9 + i];
    stage_rows(p1 + (size_t)n * 16 * 576, lds, 16, 576, 24, 24, -1, 26, tid, 192, false);
    if (tid < 144) {
        int py = tid / 12, px = tid % 12;
        float bv = b[co];
        float s[2][2] = {{bv, bv}, {bv, bv}};
        for (int ci = 0; ci < 16; ++ci) {
            const float* chp = lds + ci * 728;
            float c[4][6];
            #pragma unroll
            for (int rr = 0; rr < 4; ++rr) {
                const float2* pr = (const float2*)(chp + (2 * py + rr) * 28);
                #pragma unroll
                for (int k = 0; k < 3; ++k) { float2 t = pr[px + k]; c[rr][2 * k] = t.x; c[rr][2 * k + 1] = t.y; }
            }
            LOAD_W9(wl, ci)
            #pragma unroll
            for (int dy = 0; dy < 3; ++dy)
                #pragma unroll
                for (int dx = 0; dx < 3; ++dx) {
                    float wv = w9[dy * 3 + dx];
                    #pragma unroll
                    for (int yy = 0; yy < 2; ++yy)
                        #pragma unroll
                        for (int xx = 0; xx < 2; ++xx)
                            s[yy][xx] = fmaf(c[yy + dy][xx + dx + 1], wv, s[yy][xx]);
                }
        }
        float* ob = e2 + (size_t)(n * 32 + co) * 576;
        float mx = -INFINITY;
        #pragma unroll
        for (int yy = 0; yy < 2; ++yy)
            #pragma unroll
            for (int xx = 0; xx < 2; ++xx) {
                float v = fmaxf(s[yy][xx], 0.f);
                ob[(2 * py + yy) * 24 + 2 * px + xx] = v;
                mx = fmaxf(mx, v);
            }
        p2[(size_t)(n * 32 + co) * 144 + py * 12 + px] = mx;
    }
}

// ---- bottleneck (r4-verified). grid 128, 192 threads ----
__global__ __launch_bounds__(192) void k_bott(const float* __restrict__ p2, const float* __restrict__ w,
                                              const float* __restrict__ b, float* __restrict__ bt) {
    int co = blockIdx.x & 63, n = blockIdx.x >> 6;
    int tid = threadIdx.x;
    __shared__ __align__(16) float lds[32 * 14 * 16];
    __shared__ __align__(16) float wl[384];
    for (int i = tid; i < 288; i += 192) wl[(i / 9) * 12 + (i % 9)] = w[(co * 32) * 9 + i];
    stage_rows(p2 + (size_t)n * 32 * 144, lds, 32, 144, 12, 12, -1, 14, tid, 192, false);
    if (tid < 144) {
        int y = tid / 12, x = tid % 12;
        float acc = b[co];
        for (int ci = 0; ci < 32; ++ci) {
            const float* chp = lds + ci * 224;
            LOAD_W9(wl, ci)
            #pragma unroll
            for (int dy = 0; dy < 3; ++dy)
                #pragma unroll
                for (int dx = 0; dx < 3; ++dx)
                    acc = fmaf(chp[(y + dy) * 16 + x + dx + 1], w9[dy * 3 + dx], acc);
        }
        bt[(size_t)(n * 64 + co) * 144 + y * 12 + x] = fmaxf(acc, 0.f);
    }
}

// ---- dec2 partial (r4-verified). grid 256, 192 threads ----
__global__ __launch_bounds__(192) void k_dec2p(const float* __restrict__ bt, const float* __restrict__ e2,
                                               const float* __restrict__ w, float* __restrict__ d2b) {
    int bx = blockIdx.x;
    int chunk = bx & 3, co = (bx >> 2) & 31, n = bx >> 7;
    int cib = chunk * 24;
    int nA = max(0, min(24, 64 - cib));
    int nB = 24 - nA;
    int tid = threadIdx.x;
    __shared__ __align__(16) float lds[24 * 26 * 28];
    __shared__ __align__(16) float wl[288];
    for (int i = tid; i < 216; i += 192) wl[(i / 9) * 12 + (i % 9)] = w[((size_t)co * 96 + cib) * 9 + i];
    stage_rows(bt + ((size_t)n * 64 + cib) * 144, lds, nA, 144, 12, 12, -1, 14, tid, 192, false);
    float* ldsB = lds + nA * 224;
    int e2c = max(0, cib + nA - 64);
    stage_rows(e2 + ((size_t)n * 32 + e2c) * 576, ldsB, nB, 576, 24, 24, -1, 26, tid, 192, false);
    if (tid < 144) {
        int y = tid / 6, qx = tid % 6;
        float acc[4] = {0.f, 0.f, 0.f, 0.f};
        int r0 = ((y - 1) >> 1) + 1;
        int yodd = y & 1;
        for (int ci = 0; ci < nA; ++ci) {
            const float* chp = lds + ci * 224;
            const float2* p0 = (const float2*)(chp + r0 * 16);
            const float2* p1 = (const float2*)(chp + (r0 + 1) * 16);
            float a0[6], a1[6], am[6];
            #pragma unroll
            for (int k = 0; k < 3; ++k) {
                float2 t0 = p0[qx + k], t1 = p1[qx + k];
                a0[2 * k] = t0.x; a0[2 * k + 1] = t0.y;
                a1[2 * k] = t1.x; a1[2 * k + 1] = t1.y;
            }
            #pragma unroll
            for (int k = 0; k < 6; ++k) am[k] = yodd ? a0[k] : a1[k];
            LOAD_W9(wl, ci)
            #pragma unroll
            for (int dy = 0; dy < 3; ++dy) {
                const float* rr = (dy == 0) ? a0 : (dy == 1 ? am : a1);
                #pragma unroll
                for (int dx = 0; dx < 3; ++dx) {
                    float wv = w9[dy * 3 + dx];
                    #pragma unroll
                    for (int j = 0; j < 4; ++j)
                        acc[j] = fmaf(rr[((j + dx - 1) >> 1) + 2], wv, acc[j]);
                }
            }
        }
        for (int ci = 0; ci < nB; ++ci) {
            const float* chp = ldsB + ci * 728;
            float bvv[3][8];
            #pragma unroll
            for (int r = 0; r < 3; ++r) {
                const float2* pr = (const float2*)(chp + (y + r) * 28);
                #pragma unroll
                for (int k = 0; k < 4; ++k) { float2 t = pr[2 * qx + k]; bvv[r][2 * k] = t.x; bvv[r][2 * k + 1] = t.y; }
            }
            LOAD_W9(wl, nA + ci)
            #pragma unroll
            for (int dy = 0; dy < 3; ++dy)
                #pragma unroll
                for (int dx = 0; dx < 3; ++dx) {
                    float wv = w9[dy * 3 + dx];
                    #pragma unroll
                    for (int j = 0; j < 4; ++j)
                        acc[j] = fmaf(bvv[dy][j + dx + 1], wv, acc[j]);
                }
        }
        float* op = d2b + ((size_t)(n * 32 + co)) * 576 + y * 24 + qx * 4;
        #pragma unroll
        for (int j = 0; j < 4; ++j) atomicAdd(op + j, acc[j]);
    }
}

// ---- dec1 partial (r4-verified). grid 384, 192 threads ----
__global__ __launch_bounds__(192) void k_dec1p(const float* __restrict__ d2b, const float* __restrict__ e1u,
                                               const float* __restrict__ w, float* __restrict__ d1b) {
    int bx = blockIdx.x;
    int strip = bx % 3;
    int chunk = (bx / 3) & 3;
    int co = (bx / 12) & 15;
    int n = bx / 192;
    int cib = chunk * 12;
    int nA = max(0, min(12, 32 - cib));
    int nB = 12 - nA;
    int y0 = strip * 16;
    int yhlo = (y0 - 1) >> 1;
    int tid = threadIdx.x;
    __shared__ __align__(16) float lds[12 * 18 * 52];
    __shared__ __align__(16) float wl[144];
    for (int i = tid; i < 108; i += 192) wl[(i / 9) * 12 + (i % 9)] = w[((size_t)co * 48 + cib) * 9 + i];
    stage_rows(d2b + ((size_t)n * 32 + cib) * 576, lds, nA, 576, 24, 24, yhlo, 10, tid, 192, true);
    float* ldsB = lds + nA * 280;
    int e1c = max(0, cib + nA - 32);
    stage_rows(e1u + ((size_t)n * 16 + e1c) * HW, ldsB, nB, HW, 48, 48, y0 - 1, 18, tid, 192, false);
    {
        int yl = tid / 12, qx = tid % 12;
        int y = y0 + yl;
        float acc[4] = {0.f, 0.f, 0.f, 0.f};
        int r0 = ((y - 1) >> 1) - yhlo;
        int yodd = y & 1;
        for (int ci = 0; ci < nA; ++ci) {
            const float* chp = lds + ci * 280;
            const float2* p0 = (const float2*)(chp + r0 * 28);
            const float2* p1 = (const float2*)(chp + (r0 + 1) * 28);
            float a0[6], a1[6], am[6];
            #pragma unroll
            for (int k = 0; k < 3; ++k) {
                float2 t0 = p0[qx + k], t1 = p1[qx + k];
                a0[2 * k] = t0.x; a0[2 * k + 1] = t0.y;
                a1[2 * k] = t1.x; a1[2 * k + 1] = t1.y;
            }
            #pragma unroll
            for (int k = 0; k < 6; ++k) am[k] = yodd ? a0[k] : a1[k];
            LOAD_W9(wl, ci)
            #pragma unroll
            for (int dy = 0; dy < 3; ++dy) {
                const float* rr = (dy == 0) ? a0 : (dy == 1 ? am : a1);
                #pragma unroll
                for (int dx = 0; dx < 3; ++dx) {
                    float wv = w9[dy * 3 + dx];
                    #pragma unroll
                    for (int j = 0; j < 4; ++j)
                        acc[j] = fmaf(rr[((j + dx - 1) >> 1) + 2], wv, acc[j]);
                }
            }
        }
        for (int ci = 0; ci < nB; ++ci) {
            const float* chp = ldsB + ci * 936;
            float bvv[3][8];
            #pragma unroll
            for (int r = 0; r < 3; ++r) {
                const float2* pr = (const float2*)(chp + (yl + r) * 52);
                #pragma unroll
                for (int k = 0; k < 4; ++k) { float2 t = pr[2 * qx + k]; bvv[r][2 * k] = t.x; bvv[r][2 * k + 1] = t.y; }
            }
            LOAD_W9(wl, nA + ci)
            #pragma unroll
            for (int dy = 0; dy < 3; ++dy)
                #pragma unroll
                for (int dx = 0; dx < 3; ++dx) {
                    float wv = w9[dy * 3 + dx];
                    #pragma unroll
                    for (int j = 0; j < 4; ++j)
                        acc[j] = fmaf(bvv[dy][j + dx + 1], wv, acc[j]);
                }
        }
        float* op = d1b + ((size_t)(n * 16 + co)) * HW + y * 48 + qx * 4;
        #pragma unroll
        for (int j = 0; j < 4; ++j) atomicAdd(op + j, acc[j]);
    }
}

// ================= k_matchx: match with INLINE q-side embedding from d1b =================
// r13 geometry (blocks [0,432) match, [432,504) out1x1; NPC 24) + qtile precompute:
// out1x1 computed ONCE per halo pixel (288) instead of 9x per tap -> prologue LDS/VALU cut ~6x.
#define NPC 24
__global__ __launch_bounds__(256, 3) void k_matchx(
        const unsigned short* __restrict__ hl, const float* __restrict__ nrm,
        const float* __restrict__ d1b, const float* __restrict__ ow,
        const float* __restrict__ obias, const float* __restrict__ ew,
        const float* __restrict__ eb,
        unsigned* __restrict__ gmd, unsigned* __restrict__ lmd,
        float* __restrict__ x3s) {
    int tid = threadIdx.x;
    if (blockIdx.x >= 432) {          // ---- out1x1 -> x3s (72 blocks) ----
        int idx = (blockIdx.x - 432) * 256 + tid;
        int q = idx % HW;
        int co = (idx / HW) & 3;
        int n = idx / 9216;
        float acc = obias[co];
        #pragma unroll
        for (int ci = 0; ci < 16; ++ci)
            acc = fmaf(fmaxf(d1b[((size_t)(n * 16 + ci)) * HW + q], 0.f), ow[co * 16 + ci], acc);
        x3s[((size_t)(n * 4 + co)) * HW + q] = acc;
        return;
    }
    int bx = blockIdx.x;
    int l = (bx & 7) * 54 + (bx >> 3);        // bijective: 432 = 8*54
    int ps = l % 3;
    int qt = (l / 3) % 18;
    int mn = l / 54;
    int n = mn & 3;
    int m = mn >> 2;

    const unsigned short* refhl = hl + ((size_t)(m * 4 + n)) * HW * 256;
    const float* na = nrm + (size_t)(m * 4 + n) * HW;
    unsigned* outd = (m == 0 ? gmd : lmd) + (size_t)n * HW;

    int qbase = qt * 128;
    int pbase = ps * 768;

    __shared__ __align__(16) float smem[10688];
    unsigned short* refl0 = (unsigned short*)smem;   // [0, 8192) floats: 2 x 16 KB (main loop)
    unsigned short* refl1 = refl0 + 32 * 256;
    float* dtile = smem;                             // ALIASES refl: 288 pix x 17 = 4896 floats, prologue only
    float* nal = smem + 8192;                        // [8192, 8960)
    float* wl  = smem + 8960;                        // [8960, 10260)
    float* nbl = smem + 10260;                       // [10260, 10388)
    float* qtile = smem + 10392;                     // [10392, 10680): 288 out1x1 halo values

    int wave = tid >> 6;
    int lane = tid & 63;
    int lr = lane >> 5;
    int lc = lane & 31;

    // ---- cooperative staging: na (P-norms), emb weights, d1b tile ----
    if (tid < 192) *(float4*)&nal[tid * 4] = *(const float4*)(na + pbase + tid * 4);
    for (int i = tid; i < 900; i += 256) wl[(i / 9) * 12 + (i % 9)] = ew[i];
    for (int i = tid; i < 100; i += 256) wl[1200 + i] = eb[i];

    int b_ = n >> 1;               // batch
    int co_ = 2 + (n & 1);         // out-channel (classes 2,3 only)
    const float* dp = d1b + (size_t)b_ * 16 * HW;
    int y0t = qbase / 48 - 1;      // first staged image row (may be -1)
    for (int i = tid; i < 1152; i += 256) {    // 16 ci x 72 pix4-groups
        int ci = i / 72;
        int pp = (i % 72) * 4;                 // pixel-local 0..284 (row-aligned: 48%4==0)
        int yy = y0t + pp / 48;
        int xx = pp % 48;
        float4 v = make_float4(0.f, 0.f, 0.f, 0.f);
        if (yy >= 0 && yy < 48) {
            v = *(const float4*)(dp + (size_t)ci * HW + yy * 48 + xx);
            v.x = fmaxf(v.x, 0.f); v.y = fmaxf(v.y, 0.f);
            v.z = fmaxf(v.z, 0.f); v.w = fmaxf(v.w, 0.f);
        }
        dtile[(pp + 0) * 17 + ci] = v.x;
        dtile[(pp + 1) * 17 + ci] = v.y;
        dtile[(pp + 2) * 17 + ci] = v.z;
        dtile[(pp + 3) * 17 + ci] = v.w;
    }
    __syncthreads();

    // ---- qtile precompute: out1x1 once per halo pixel (same FMA sequence as before) ----
    float owr[16];
    #pragma unroll
    for (int k = 0; k < 16; ++k) owr[k] = ow[co_ * 16 + k];
    float obv = obias[co_];
    for (int i = tid; i < 288; i += 256) {
        float v = obv;
        const float* dpix = &dtile[i * 17];
        #pragma unroll
        for (int ci = 0; ci < 16; ++ci) v = fmaf(dpix[ci], owr[ci], v);
        qtile[i] = v;
    }
    __syncthreads();

    // ---- inline q-side embedding: each lane computes exactly its MFMA fragment slice ----
    short8 ahi[2][4], alo[2][4];
    int eb0 = (lane >> 4) * 8;
    #pragma unroll
    for (int j = 0; j < 2; ++j) {
        int rloc = wave * 32 + j * 16 + (lane & 15);
        int r = qbase + rloc;
        int x = r % 48, y = r / 48;
        float p9[9];
        #pragma unroll
        for (int ky = 0; ky < 3; ++ky)
            #pragma unroll
            for (int kx = 0; kx < 3; ++kx) {
                int yy = y + ky - 1, xx = x + kx - 1;
                float v = 0.f;
                if (yy >= 0 && yy < 48 && xx >= 0 && xx < 48)
                    v = qtile[(yy - y0t) * 48 + xx];
                p9[ky * 3 + kx] = v;
            }
        float nsum = 0.f;
        #pragma unroll
        for (int ks = 0; ks < 4; ++ks) {
            short8 vh, vlo;
            #pragma unroll
            for (int t = 0; t < 8; ++t) {
                int e = ks * 32 + eb0 + t;
                float v = 0.f;
                if (e < 100) {
                    v = wl[1200 + e];
                    #pragma unroll
                    for (int k = 0; k < 9; ++k) v = fmaf(p9[k], wl[e * 12 + k], v);
                    nsum = fmaf(v, v, nsum);
                }
                unsigned bits = __float_as_uint(v);
                vh[t] = (short)(bits >> 16);
                float lo = v - __uint_as_float(bits & 0xFFFF0000u);
                vlo[t] = (short)(__float_as_uint(lo) >> 16);
            }
            ahi[j][ks] = vh;
            alo[j][ks] = vlo;
        }
        // full row norm: lanes {L, L+16, L+32, L+48} hold disjoint 32-dim slices of row rloc
        nsum += __shfl_xor(nsum, 16, 64);
        nsum += __shfl_xor(nsum, 32, 64);
        if ((lane >> 4) == 0) nbl[rloc] = nsum;
    }
    __syncthreads();   // dtile/qtile reads done -> refl region may be overwritten

    // ---- prologue: stage ref chunk 0 ----
    {
        const unsigned short* gb = refhl + (size_t)pbase * 256;
        #pragma unroll
        for (int t = 0; t < 4; ++t) {
            int i = wave * 4 + t;
            int r = 2 * i + lr;
            gll16(gb + (size_t)r * 256 + (lc ^ (r & 7)) * 8, refl0 + i * 512);
        }
    }
    asm volatile("s_waitcnt lgkmcnt(0)" ::: "memory");

    float dmin[2][4];
    #pragma unroll
    for (int j = 0; j < 2; ++j)
        #pragma unroll
        for (int r = 0; r < 4; ++r) dmin[j][r] = INFINITY;

    for (int pc = 0; pc < NPC; ++pc) {
        unsigned short* cur = (pc & 1) ? refl1 : refl0;
        unsigned short* nxt = (pc & 1) ? refl0 : refl1;
        if (pc + 1 < NPC) {
            const unsigned short* gb = refhl + (size_t)(pbase + (pc + 1) * 32) * 256;
            #pragma unroll
            for (int t = 0; t < 4; ++t) {
                int i = wave * 4 + t;
                int r = 2 * i + lr;
                gll16(gb + (size_t)r * 256 + (lc ^ (r & 7)) * 8, nxt + i * 512);
            }
            asm volatile("s_waitcnt vmcnt(4)" ::: "memory");
        } else {
            asm volatile("s_waitcnt vmcnt(0)" ::: "memory");
        }
        __builtin_amdgcn_s_barrier();

        short8 bhi[2][4], blo[2][4];
        #pragma unroll
        for (int ptile = 0; ptile < 2; ++ptile) {
            int r = ptile * 16 + (lane & 15);
            #pragma unroll
            for (int ks = 0; ks < 4; ++ks) {
                int cg = ks * 4 + (lane >> 4);
                const char* p = (const char*)cur + r * 512 + ((cg ^ (r & 7)) << 4);
                bhi[ptile][ks] = *(const short8*)p;
                blo[ptile][ks] = *(const short8*)(p + 256);
            }
        }

        f32x4 acc[2][2];
        #pragma unroll
        for (int ptile = 0; ptile < 2; ++ptile)
            #pragma unroll
            for (int j = 0; j < 2; ++j) acc[ptile][j] = (f32x4){0.f, 0.f, 0.f, 0.f};

        #pragma unroll
        for (int ks = 0; ks < 4; ++ks) {
            #pragma unroll
            for (int ptile = 0; ptile < 2; ++ptile)
                #pragma unroll
                for (int j = 0; j < 2; ++j)
                    acc[ptile][j] = __builtin_amdgcn_mfma_f32_16x16x32_bf16(
                        ahi[j][ks], bhi[ptile][ks], acc[ptile][j], 0, 0, 0);
            #pragma unroll
            for (int ptile = 0; ptile < 2; ++ptile)
                #pragma unroll
                for (int j = 0; j < 2; ++j)
                    acc[ptile][j] = __builtin_amdgcn_mfma_f32_16x16x32_bf16(
                        ahi[j][ks], blo[ptile][ks], acc[ptile][j], 0, 0, 0);
            #pragma unroll
            for (int ptile = 0; ptile < 2; ++ptile)
                #pragma unroll
                for (int j = 0; j < 2; ++j)
                    acc[ptile][j] = __builtin_amdgcn_mfma_f32_16x16x32_bf16(
                        alo[j][ks], bhi[ptile][ks], acc[ptile][j], 0, 0, 0);
        }

        #pragma unroll
        for (int ptile = 0; ptile < 2; ++ptile) {
            float nav = nal[pc * 32 + ptile * 16 + (lane & 15)];
            #pragma unroll
            for (int j = 0; j < 2; ++j)
                #pragma unroll
                for (int r = 0; r < 4; ++r)
                    dmin[j][r] = fminf(dmin[j][r], fmaf(-2.f, acc[ptile][j][r], nav));
        }
        __builtin_amdgcn_s_barrier();
    }

    #pragma unroll
    for (int j = 0; j < 2; ++j)
        #pragma unroll
        for (int r = 0; r < 4; ++r) {
            float v = dmin[j][r];
            v = fminf(v, __shfl_xor(v, 1, 64));
            v = fminf(v, __shfl_xor(v, 2, 64));
            v = fminf(v, __shfl_xor(v, 4, 64));
            v = fminf(v, __shfl_xor(v, 8, 64));
            if ((lane & 15) == 0) {
                int qloc = wave * 32 + j * 16 + 4 * (lane >> 4) + r;
                float d2 = fmaxf(v + nbl[qloc], 0.f);
                atomicMin(&outd[qbase + qloc], __float_as_uint(d2));
            }
        }
}

// ---- final dsh conv (r4-verified) ----
__global__ void k_final(const float* __restrict__ x3s, const unsigned* __restrict__ gmd,
                        const unsigned* __restrict__ lmd, const float* __restrict__ x2,
                        const float* __restrict__ dshw, const float* __restrict__ dshb,
                        float* __restrict__ out) {
    int idx = blockIdx.x * THREADS + threadIdx.x;
    if (idx >= 9216) return;
    int q = idx % HW, ni = idx / HW;
    int n = 2 + (ni & 1) + 4 * (ni >> 1);
    int b = ni >> 1;
    int x = q % 48, y = q / 48;
    float acc = dshb[0];
    for (int c = 0; c < 7; ++c) {
        const float* wp = dshw + c * 9;
        #pragma unroll
        for (int ky = 0; ky < 3; ++ky) {
            int yy = y + ky - 1;
            if (yy < 0 || yy >= 48) continue;
            #pragma unroll
            for (int kx = 0; kx < 3; ++kx) {
                int xx = x + kx - 1;
                if (xx < 0 || xx >= 48) continue;
                float v;
                if (c < 4) v = x3s[(size_t)(b * 4 + c) * HW + yy * 48 + xx];
                else if (c == 4) {
                    float d2 = __uint_as_float(gmd[(size_t)ni * HW + yy * 48 + xx]);
                    v = 1.f - 2.f / (1.f + expf(d2));
                } else if (c == 5) {
                    float d2 = __uint_as_float(lmd[(size_t)ni * HW + yy * 48 + xx]);
                    v = 1.f - 2.f / (1.f + expf(d2));
                } else v = x2[(size_t)n * HW + yy * 48 + xx];
                acc = fmaf(v, wp[ky * 3 + kx], acc);
            }
        }
    }
    out[idx] = acc;
}

extern "C" void kernel_launch(void* const* d_in, const int* in_sizes, int n_in,
                              void* d_out, int out_size, void* d_ws, size_t ws_size,
                              hipStream_t stream) {
    const float* x1     = (const float*)d_in[0];
    const float* x2     = (const float*)d_in[1];
    const float* x3     = (const float*)d_in[2];
    const float* enc1_w = (const float*)d_in[3];
    const float* enc1_b = (const float*)d_in[4];
    const float* enc2_w = (const float*)d_in[5];
    const float* enc2_b = (const float*)d_in[6];
    const float* bott_w = (const float*)d_in[7];
    const float* bott_b = (const float*)d_in[8];
    const float* dec2_w = (const float*)d_in[9];
    const float* dec2_b = (const float*)d_in[10];
    const float* dec1_w = (const float*)d_in[11];
    const float* dec1_b = (const float*)d_in[12];
    const float* out_w  = (const float*)d_in[13];
    const float* out_b  = (const float*)d_in[14];
    const float* emb_w  = (const float*)d_in[15];
    const float* emb_b  = (const float*)d_in[16];
    const float* dsh_w  = (const float*)d_in[17];
    const float* dsh_b  = (const float*)d_in[18];

    float* w = (float*)d_ws;
    float* e1u  = w;                   // [0, 73728)
    float* p1   = w + 73728;           // [73728, 92160)
    float* e2   = w + 92160;           // [92160, 129024)
    float* p2   = w + 129024;          // [129024, 138240)
    float* bt   = w + 138240;          // [138240, 156672)
    float* d2b  = w + 156672;          // [156672, 193536)
    float* d1b  = w + 193536;          // [193536, 267264)
    float* x3s  = w + 267264;          // [267264, 285696)
    float* nrm  = w + 285696;          // [285696, 313344)
    unsigned* gmd = (unsigned*)(w + 313344);   // [313344, 322560)
    unsigned* lmd = (unsigned*)(w + 322560);   // [322560, 331776)
    unsigned short* hl = (unsigned short*)(w + 331776);  // arr0/arr1 used only

    k_pre<<<dim3(608), dim3(256), 0, stream>>>(d2b, d1b, dec2_b, dec1_b, x1, x2, emb_w, emb_b,
                                               hl, nrm, gmd, x3, enc1_w, enc1_b, e1u, p1);
    k_enc2pool<<<dim3(64), dim3(192), 0, stream>>>(p1, enc2_w, enc2_b, e2, p2);
    k_bott<<<dim3(128), dim3(192), 0, stream>>>(p2, bott_w, bott_b, bt);
    k_dec2p<<<dim3(256), dim3(192), 0, stream>>>(bt, e2, dec2_w, d2b);
    k_dec1p<<<dim3(384), dim3(192), 0, stream>>>(d2b, e1u, dec1_w, d1b);
    k_matchx<<<dim3(504), dim3(256), 0, stream>>>(hl, nrm, d1b, out_w, out_b, emb_w, emb_b,
                                                  gmd, lmd, x3s);
    k_final<<<dim3(36), dim3(THREADS), 0, stream>>>(x3s, gmd, lmd, x2, dsh_w, dsh_b, (float*)d_out);
}